// Round 11
// baseline (8072.293 us; speedup 1.0000x reference)
//
#include <hip/hip_runtime.h>

// Net_46076409152296: spiking net fwd (RLeaky + Leaky). B=1024,T=32,D=2312,H=512,O=10.
// d_out fp32. v11: occupancy restructure of the passing v10.
//   - 1024 blocks x 512 threads (1 batch row/block, 1 hidden unit/thread)
//   - f64 accumulation for all dots (correctly-rounded fp32 results; identical
//     ascending fma order as v10 for fc1/rec), fp32 state updates unchanged
//   - x staged 64 k at a time (one LDS element/thread, 64x fewer barriers)
//   - spikes kept as f64 in LDS (no per-MAC cvt of the spike operand)
//   - fc2 spread over 320 threads (32 lanes/output, f64 shfl butterfly)
// LDS: xs 4KB + spkd 4KB + cur1 16KB = 24KB -> 4 blocks/CU (grid-capped).

__global__ __launch_bounds__(512) void Net_46076409152296_kernel(
    const float* __restrict__ x, const float* __restrict__ W1,
    const float* __restrict__ b1, const float* __restrict__ Wr,
    const float* __restrict__ br, const float* __restrict__ W2,
    const float* __restrict__ b2, float* __restrict__ out) {
  const int B = 1024, T = 32, D = 2312, H = 512, O = 10;
  // TC=8 steps/chunk, 4 chunks. D = 36*64 + 8.

  __shared__ double xs[8][64];     // staged x slab (f64): 4 KB
  __shared__ double spkd[512];     // current spikes as f64: 4 KB
  __shared__ float  cur1[8][512];  // fc1 results for the chunk: 16 KB

  const int j = threadIdx.x;       // 0..511, owns hidden unit h=j
  const int b0 = blockIdx.x;       // batch row

  float m1 = 0.0f;                 // mem1[b0][j]
  float m2 = 0.0f;                 // mem2[b0][o] (only group leaders use it)

  spkd[j] = 0.0;                   // visible via first chunk's staging barrier

  const float b1r = b1[j];
  const float brr = br[j];
  const float* __restrict__ w1p = W1 + (size_t)j * D;
  const float* __restrict__ wrp = Wr + (size_t)j * H;

  // fc2 role: threads 0..319 -> output o = j>>5, lane l = j&31
  const int o = j >> 5;
  const int l = j & 31;
  const float b2r = (j < 320 && l == 0) ? b2[o] : 0.0f;

  // x staging role: thread j stages xs[ts][ks]
  const int ts = j >> 6;           // 0..7 (time within chunk)
  const int ks = j & 63;           // 0..63 (k within slab)
  const float* __restrict__ xstage = x + ((size_t)b0 * T + ts) * D + ks;

  for (int c = 0; c < 4; ++c) {
    const int tbase = c * 8;

    // ---- fc1: acc[m] = dot_f64(x[b0, tbase+m, :], W1[j,:]) ----
    double acc[8];
#pragma unroll
    for (int m = 0; m < 8; ++m) acc[m] = 0.0;

    const float* __restrict__ xc = xstage + (size_t)tbase * D;
    int k0 = 0;
    for (; k0 + 64 <= D; k0 += 64) {
      __syncthreads();                       // previous slab fully consumed
      xs[ts][ks] = (double)xc[k0];
      __syncthreads();                       // new slab visible
      for (int kk = 0; kk < 64; kk += 4) {
        const float4 w4 = *(const float4*)(w1p + k0 + kk);
        const double w0 = w4.x, w1d = w4.y, w2d = w4.z, w3d = w4.w;
#pragma unroll
        for (int m = 0; m < 8; ++m) {
          const double2 xa = *(const double2*)&xs[m][kk];
          const double2 xb = *(const double2*)&xs[m][kk + 2];
          acc[m] = fma(xb.y, w3d,
                   fma(xb.x, w2d, fma(xa.y, w1d, fma(xa.x, w0, acc[m]))));
        }
      }
    }
    {  // k tail: 8 remaining (k0 == 2304)
      __syncthreads();
      if (j < 64)
        xs[j >> 3][j & 7] =
            (double)x[((size_t)b0 * T + tbase + (j >> 3)) * D + k0 + (j & 7)];
      __syncthreads();
      for (int kk = 0; kk < 8; kk += 4) {
        const float4 w4 = *(const float4*)(w1p + k0 + kk);
        const double w0 = w4.x, w1d = w4.y, w2d = w4.z, w3d = w4.w;
#pragma unroll
        for (int m = 0; m < 8; ++m) {
          const double2 xa = *(const double2*)&xs[m][kk];
          const double2 xb = *(const double2*)&xs[m][kk + 2];
          acc[m] = fma(xb.y, w3d,
                   fma(xb.x, w2d, fma(xa.y, w1d, fma(xa.x, w0, acc[m]))));
        }
      }
    }
    __syncthreads();  // xs reads done; also guards cur1 overwrite vs prior scan
#pragma unroll
    for (int m = 0; m < 8; ++m) cur1[m][j] = __fadd_rn((float)acc[m], b1r);
    __syncthreads();  // cur1 ready

    // ---- scan: 8 recurrent steps ----
    for (int tt = 0; tt < 8; ++tt) {
      double rec = 0.0;
      for (int k = 0; k < H; k += 4) {
        const float4 w4 = *(const float4*)(wrp + k);
        const double2 sa = *(const double2*)&spkd[k];
        const double2 sb = *(const double2*)&spkd[k + 2];
        rec = fma(sb.y, (double)w4.w,
              fma(sb.x, (double)w4.z,
              fma(sa.y, (double)w4.y, fma(sa.x, (double)w4.x, rec))));
      }
      __syncthreads();  // all reads of old spikes complete
      {
        // mem1 = ((0.99*mem1 + cur1) + (rec + br)) - reset   (non-fused fp32)
        const float rst = (m1 - 1.0f > 0.0f) ? 1.0f : 0.0f;
        const float mn = __fsub_rn(
            __fadd_rn(__fadd_rn(__fmul_rn(0.99f, m1), cur1[tt][j]),
                      __fadd_rn((float)rec, brr)),
            rst);
        m1 = mn;
        spkd[j] = (mn - 1.0f > 0.0f) ? 1.0 : 0.0;
      }
      __syncthreads();  // new spikes visible
      // fc2 + mem2 + outputs: 32 lanes per output neuron, stride-32 k.
      if (j < 320) {
        const float* __restrict__ w2p = W2 + (size_t)o * H;
        double p = 0.0;
#pragma unroll
        for (int s = 0; s < 16; ++s) {
          const int k = l + 32 * s;
          p = fma(spkd[k], (double)w2p[k], p);
        }
#pragma unroll
        for (int off = 16; off; off >>= 1) p += __shfl_down(p, off, 32);
        if (l == 0) {
          const float cur2 = __fadd_rn((float)p, b2r);
          const float rst2 = (m2 - 1.0f > 0.0f) ? 1.0f : 0.0f;
          const float mn2 =
              __fsub_rn(__fadd_rn(__fmul_rn(0.99f, m2), cur2), rst2);
          m2 = mn2;
          const int t = tbase + tt;
          const size_t oidx = ((size_t)t * B + b0) * O + o;
          out[oidx] = (mn2 - 1.0f > 0.0f) ? 1.0f : 0.0f;  // spk2
          out[(size_t)T * B * O + oidx] = mn2;            // mem2
        }
      }
      // next step only READS spkd before its post-rec barrier -> race-free.
    }
  }
}

extern "C" void kernel_launch(void* const* d_in, const int* in_sizes, int n_in,
                              void* d_out, int out_size, void* d_ws, size_t ws_size,
                              hipStream_t stream) {
  const float* x  = (const float*)d_in[0];
  const float* W1 = (const float*)d_in[1];
  const float* b1 = (const float*)d_in[2];
  const float* Wr = (const float*)d_in[3];
  const float* br = (const float*)d_in[4];
  const float* W2 = (const float*)d_in[5];
  const float* b2 = (const float*)d_in[6];
  float* out = (float*)d_out;  // FP32
  (void)in_sizes; (void)n_in; (void)out_size; (void)d_ws; (void)ws_size;

  Net_46076409152296_kernel<<<1024, 512, 0, stream>>>(
      x, W1, b1, Wr, br, W2, b2, out);
}

// Round 12
// 4120.572 us; speedup vs baseline: 1.9590x; 1.9590x over previous
//
#include <hip/hip_runtime.h>

// Net_46076409152296: spiking net fwd (RLeaky + Leaky). B=1024,T=32,D=2312,H=512,O=10.
// d_out fp32. v12: VALU-efficiency restructure of passing v10/v11 (identical math:
// f64 ascending-k dots -> fp32, non-fused fp32 state updates).
//  - grid 256 x 512 thr; block owns 4 batch rows; thread j owns hidden unit j
//  - rec: 4 independent f64 chains/thread, Wr f32 load + cvt shared across rows
//  - fc1: acc[4][8] f64 in regs; x staged as f64 in ping-pong LDS slabs (1 bar/slab)
//  - cur1 stays in REGISTERS through the scan (v11 wastefully round-tripped LDS)
//  - fc2: 320 threads, 8 lanes/output-dot, f64 shfl-tree reduce
// LDS: xs 32KB + spkd 16KB = 48KB. ~8 waves/CU by design (ILP covers latency).

__global__ __launch_bounds__(512) void Net_46076409152296_kernel(
    const float* __restrict__ x, const float* __restrict__ W1,
    const float* __restrict__ b1, const float* __restrict__ Wr,
    const float* __restrict__ br, const float* __restrict__ W2,
    const float* __restrict__ b2, float* __restrict__ out) {
  const int B = 1024, T = 32, D = 2312, H = 512, O = 10;
  // TC=8 steps/chunk, 4 chunks; D = 36*64 + 8 slabs.

  __shared__ double xs[2][4][8][64];  // ping-pong staged x (f64): 32 KB
  __shared__ double spkd[4][512];     // current spikes as f64: 16 KB

  const int j = threadIdx.x;          // 0..511, owns hidden unit h=j
  const int b0 = blockIdx.x << 2;     // first of 4 batch rows

  float m1[4] = {0.f, 0.f, 0.f, 0.f};
  float m2 = 0.f;

#pragma unroll
  for (int r = 0; r < 4; ++r) spkd[r][j] = 0.0;  // visible via first stage bar

  const float b1r = b1[j];
  const float brr = br[j];
  const float* __restrict__ w1p = W1 + (size_t)j * D;
  const float* __restrict__ wrp = Wr + (size_t)j * H;

  // fc2 role: groups of 8 lanes; g = j>>3 in [0,40): r2 = g/10, o2 = g%10
  const int g = j >> 3, l = j & 7;
  const int r2 = g / 10, o2 = g - r2 * 10;
  const bool doB = (j < 320);
  const float b2v = doB ? b2[o2] : 0.f;
  const float* __restrict__ w2p = doB ? (W2 + (size_t)o2 * H) : W2;

  // staging helpers -----------------------------------------------------
  const int ks2 = (j & 31) << 1;   // k pair within slab
  const int phi = j >> 5;          // 0..15
  auto stage64 = [&](int bb, int tbase, int kbase) {
#pragma unroll
    for (int d = 0; d < 2; ++d) {
      const int p = phi + (d << 4);       // 0..31 = r*8 + tt
      const int r = p >> 3, tt = p & 7;
      const float2 v = *(const float2*)(
          x + ((size_t)(b0 + r) * T + tbase + tt) * D + kbase + ks2);
      double2 dv; dv.x = (double)v.x; dv.y = (double)v.y;
      *(double2*)&xs[bb][r][tt][ks2] = dv;
    }
  };
  auto stage8 = [&](int bb, int tbase, int kbase) {
    if (j < 256) {
      const int r = j >> 6, tt = (j >> 3) & 7, kk = j & 7;
      xs[bb][r][tt][kk] =
          (double)x[((size_t)(b0 + r) * T + tbase + tt) * D + kbase + kk];
    }
  };

  int buf = 0;
  for (int c = 0; c < 4; ++c) {
    const int tbase = c << 3;

    // ---- fc1: acc[r][m] = dot_f64(x[b0+r, tbase+m, :], W1[j,:]) ----
    double acc[4][8];
#pragma unroll
    for (int r = 0; r < 4; ++r)
#pragma unroll
      for (int m = 0; m < 8; ++m) acc[r][m] = 0.0;

    stage64(buf, tbase, 0);
    __syncthreads();
    int kof = 0;
    for (int s = 0; s < 37; ++s) {
      const int w = (s < 36) ? 64 : 8;
      if (s < 35) stage64(buf ^ 1, tbase, kof + 64);
      else if (s == 35) stage8(buf ^ 1, tbase, kof + 64);
      for (int kk = 0; kk < w; kk += 4) {
        const float4 w4 = *(const float4*)(w1p + kof + kk);
        const double w0 = w4.x, w1d = w4.y, w2d = w4.z, w3d = w4.w;
#pragma unroll
        for (int r = 0; r < 4; ++r)
#pragma unroll
          for (int m = 0; m < 8; ++m) {
            const double2 xa = *(const double2*)&xs[buf][r][m][kk];
            const double2 xb = *(const double2*)&xs[buf][r][m][kk + 2];
            acc[r][m] = fma(xb.y, w3d,
                        fma(xb.x, w2d, fma(xa.y, w1d, fma(xa.x, w0, acc[r][m]))));
          }
      }
      __syncthreads();
      buf ^= 1;
      kof += w;
    }

    // cur1 stays in registers: c1[r][m] = fp32(dot) + b1 (same as v10/v11)
    float c1[4][8];
#pragma unroll
    for (int r = 0; r < 4; ++r)
#pragma unroll
      for (int m = 0; m < 8; ++m) c1[r][m] = __fadd_rn((float)acc[r][m], b1r);

    // ---- scan: 8 recurrent steps (unrolled so c1[r][tt] is static) ----
#pragma unroll
    for (int tt = 0; tt < 8; ++tt) {
      double rec[4] = {0.0, 0.0, 0.0, 0.0};
      for (int k = 0; k < H; k += 4) {
        const float4 w4 = *(const float4*)(wrp + k);
        const double w0 = w4.x, w1d = w4.y, w2d = w4.z, w3d = w4.w;
#pragma unroll
        for (int r = 0; r < 4; ++r) {
          const double2 sa = *(const double2*)&spkd[r][k];
          const double2 sb = *(const double2*)&spkd[r][k + 2];
          rec[r] = fma(sb.y, w3d,
                   fma(sb.x, w2d, fma(sa.y, w1d, fma(sa.x, w0, rec[r]))));
        }
      }
      __syncthreads();  // all reads of old spikes complete
#pragma unroll
      for (int r = 0; r < 4; ++r) {
        const float rst = (m1[r] - 1.0f > 0.0f) ? 1.0f : 0.0f;
        const float mn = __fsub_rn(
            __fadd_rn(__fadd_rn(__fmul_rn(0.99f, m1[r]), c1[r][tt]),
                      __fadd_rn((float)rec[r], brr)),
            rst);
        m1[r] = mn;
        spkd[r][j] = (mn - 1.0f > 0.0f) ? 1.0 : 0.0;
      }
      __syncthreads();  // new spikes visible
      // fc2 + mem2 + outputs (8 lanes per (row,output) dot)
      if (doB) {
        double p = 0.0;
#pragma unroll
        for (int s8 = 0; s8 < 64; ++s8) {
          const int k = l + (s8 << 3);
          p = fma(spkd[r2][k], (double)w2p[k], p);
        }
        p += __shfl_down(p, 4, 8);
        p += __shfl_down(p, 2, 8);
        p += __shfl_down(p, 1, 8);
        if (l == 0) {
          const float cur2 = __fadd_rn((float)p, b2v);
          const float rst2 = (m2 - 1.0f > 0.0f) ? 1.0f : 0.0f;
          const float mn2 =
              __fsub_rn(__fadd_rn(__fmul_rn(0.99f, m2), cur2), rst2);
          m2 = mn2;
          const int t = tbase + tt;
          const size_t oidx = ((size_t)t * B + (b0 + r2)) * O + o2;
          out[oidx] = (mn2 - 1.0f > 0.0f) ? 1.0f : 0.0f;  // spk2
          out[(size_t)T * B * O + oidx] = mn2;            // mem2
        }
      }
      // next step only READS spkd before its post-rec barrier -> race-free
    }
  }
}

extern "C" void kernel_launch(void* const* d_in, const int* in_sizes, int n_in,
                              void* d_out, int out_size, void* d_ws, size_t ws_size,
                              hipStream_t stream) {
  const float* x  = (const float*)d_in[0];
  const float* W1 = (const float*)d_in[1];
  const float* b1 = (const float*)d_in[2];
  const float* Wr = (const float*)d_in[3];
  const float* br = (const float*)d_in[4];
  const float* W2 = (const float*)d_in[5];
  const float* b2 = (const float*)d_in[6];
  float* out = (float*)d_out;  // FP32
  (void)in_sizes; (void)n_in; (void)out_size; (void)d_ws; (void)ws_size;

  Net_46076409152296_kernel<<<256, 512, 0, stream>>>(
      x, W1, b1, Wr, br, W2, b2, out);
}

// Round 13
// 3692.353 us; speedup vs baseline: 2.1862x; 1.1160x over previous
//
#include <hip/hip_runtime.h>

// Net_46076409152296: spiking net fwd (RLeaky+Leaky). B=1024,T=32,D=2312,H=512,O=10.
// v13: two-kernel split, attacking the measured LDS-pipe bound of v12.
//  K1: cur1[(b*T+t)][h] = f64dot(x_row, W1_row) + b1  — classic 128x128 tiled
//      GEMM, f32 LDS tiles (ping-pong), f64 accum in regs (cvt in-loop), f32 out
//      to d_ws. VALU-bound by design (~80% fma fraction).
//  K2: recurrent scan; spikes as f32 in LDS ((double)spike exact for {0,1}),
//      Wr rows streamed from L2 per thread, cur1 read coalesced from ws,
//      fc2 on 320 threads (8-lane f64 dots + shfl). fp32 state updates
//      identical to v10/v12. f64 accumulation makes summation-order changes
//      fp32-invisible (slack ~2^18), so tiling order is free.

constexpr int Bq = 1024, Tq = 32, Dq = 2312, Hq = 512, Oq = 10;

// ---------------- K1: tiled GEMM, C[m][n] = dot(x[m,:], W1[n,:]) + b1[n]
__global__ __launch_bounds__(256) void snn_fc1_gemm(
    const float* __restrict__ x, const float* __restrict__ W1,
    const float* __restrict__ b1, float* __restrict__ cur1) {
  __shared__ float As[2][8][128];
  __shared__ float Bs[2][8][128];
  const int tid = threadIdx.x;
  const int tx = tid & 15;        // n dir
  const int ty = tid >> 4;        // m dir
  const size_t m0 = (size_t)blockIdx.y * 128;
  const int n0 = blockIdx.x * 128;
  const int srow = tid >> 1;             // 0..127
  const int sko = (tid & 1) * 4;         // 0 or 4
  const float* __restrict__ ax = x + (m0 + srow) * Dq + sko;
  const float* __restrict__ bx = W1 + (size_t)(n0 + srow) * Dq + sko;

  double acc[8][8];
#pragma unroll
  for (int i = 0; i < 8; ++i)
#pragma unroll
    for (int j = 0; j < 8; ++j) acc[i][j] = 0.0;

  // prologue: load slab 0 into regs, write to LDS[0]
  float4 av = *(const float4*)(ax);
  float4 bv = *(const float4*)(bx);
  As[0][sko + 0][srow] = av.x; As[0][sko + 1][srow] = av.y;
  As[0][sko + 2][srow] = av.z; As[0][sko + 3][srow] = av.w;
  Bs[0][sko + 0][srow] = bv.x; Bs[0][sko + 1][srow] = bv.y;
  Bs[0][sko + 2][srow] = bv.z; Bs[0][sko + 3][srow] = bv.w;
  __syncthreads();

  for (int s = 0; s < 289; ++s) {        // D = 289 * 8
    const int buf = s & 1;
    if (s + 1 < 289) {                   // issue next-slab loads early
      av = *(const float4*)(ax + (s + 1) * 8);
      bv = *(const float4*)(bx + (s + 1) * 8);
    }
#pragma unroll
    for (int kk = 0; kk < 8; ++kk) {
      float a[8], b[8];
      *(float4*)&a[0] = *(const float4*)&As[buf][kk][ty * 8];
      *(float4*)&a[4] = *(const float4*)&As[buf][kk][ty * 8 + 4];
      *(float4*)&b[0] = *(const float4*)&Bs[buf][kk][tx * 8];
      *(float4*)&b[4] = *(const float4*)&Bs[buf][kk][tx * 8 + 4];
      double ad[8], bd[8];
#pragma unroll
      for (int i = 0; i < 8; ++i) { ad[i] = (double)a[i]; bd[i] = (double)b[i]; }
#pragma unroll
      for (int i = 0; i < 8; ++i)
#pragma unroll
        for (int j = 0; j < 8; ++j) acc[i][j] = fma(ad[i], bd[j], acc[i][j]);
    }
    if (s + 1 < 289) {
      const int nb = buf ^ 1;
      As[nb][sko + 0][srow] = av.x; As[nb][sko + 1][srow] = av.y;
      As[nb][sko + 2][srow] = av.z; As[nb][sko + 3][srow] = av.w;
      Bs[nb][sko + 0][srow] = bv.x; Bs[nb][sko + 1][srow] = bv.y;
      Bs[nb][sko + 2][srow] = bv.z; Bs[nb][sko + 3][srow] = bv.w;
      __syncthreads();
    }
  }

  float bl[8];
  *(float4*)&bl[0] = *(const float4*)(b1 + n0 + tx * 8);
  *(float4*)&bl[4] = *(const float4*)(b1 + n0 + tx * 8 + 4);
#pragma unroll
  for (int i = 0; i < 8; ++i) {
    float* crow = cur1 + (m0 + ty * 8 + i) * Hq + n0 + tx * 8;
    float4 v0, v1;
    v0.x = __fadd_rn((float)acc[i][0], bl[0]);
    v0.y = __fadd_rn((float)acc[i][1], bl[1]);
    v0.z = __fadd_rn((float)acc[i][2], bl[2]);
    v0.w = __fadd_rn((float)acc[i][3], bl[3]);
    v1.x = __fadd_rn((float)acc[i][4], bl[4]);
    v1.y = __fadd_rn((float)acc[i][5], bl[5]);
    v1.z = __fadd_rn((float)acc[i][6], bl[6]);
    v1.w = __fadd_rn((float)acc[i][7], bl[7]);
    *(float4*)(crow) = v0;
    *(float4*)(crow + 4) = v1;
  }
}

// ---------------- K2: recurrent scan (rec + mem1/spk + fc2 + outputs)
__global__ __launch_bounds__(512) void snn_scan(
    const float* __restrict__ cur1, const float* __restrict__ Wr,
    const float* __restrict__ br, const float* __restrict__ W2,
    const float* __restrict__ b2, float* __restrict__ out, int b_off) {
  __shared__ float spkF[4][512];   // 8 KB

  const int j = threadIdx.x;       // hidden unit
  const int lb = blockIdx.x * 4;   // local first row (within this ws chunk)
  const int gb = b_off + lb;       // global first batch row

  float m1[4] = {0.f, 0.f, 0.f, 0.f};
  float m2 = 0.f;
#pragma unroll
  for (int r = 0; r < 4; ++r) spkF[r][j] = 0.f;
  __syncthreads();

  const float brr = br[j];
  const float* __restrict__ wrp = Wr + (size_t)j * Hq;

  const int g = j >> 3, l = j & 7;
  const int r2 = g / 10, o2 = g - r2 * 10;
  const bool doB = (j < 320);
  const float b2v = doB ? b2[o2] : 0.f;
  const float* __restrict__ w2p = doB ? (W2 + (size_t)o2 * Hq) : W2;

  for (int t = 0; t < Tq; ++t) {
    // prefetch this step's cur1 (coalesced)
    float c1[4];
#pragma unroll
    for (int r = 0; r < 4; ++r)
      c1[r] = cur1[((size_t)(lb + r) * Tq + t) * Hq + j];

    double rec[4] = {0.0, 0.0, 0.0, 0.0};
    for (int k = 0; k < Hq; k += 4) {
      const float4 w4 = *(const float4*)(wrp + k);
      const double w0 = (double)w4.x, w1d = (double)w4.y;
      const double w2d = (double)w4.z, w3d = (double)w4.w;
#pragma unroll
      for (int r = 0; r < 4; ++r) {
        const float4 s4 = *(const float4*)&spkF[r][k];
        rec[r] = fma((double)s4.w, w3d,
                 fma((double)s4.z, w2d,
                 fma((double)s4.y, w1d, fma((double)s4.x, w0, rec[r]))));
      }
    }
    __syncthreads();  // all reads of old spikes complete
#pragma unroll
    for (int r = 0; r < 4; ++r) {
      const float rst = (m1[r] - 1.0f > 0.0f) ? 1.0f : 0.0f;
      const float mn = __fsub_rn(
          __fadd_rn(__fadd_rn(__fmul_rn(0.99f, m1[r]), c1[r]),
                    __fadd_rn((float)rec[r], brr)),
          rst);
      m1[r] = mn;
      spkF[r][j] = (mn - 1.0f > 0.0f) ? 1.0f : 0.0f;
    }
    __syncthreads();  // new spikes visible
    if (doB) {
      double p = 0.0;
#pragma unroll
      for (int s8 = 0; s8 < 64; ++s8) {
        const int k = l + (s8 << 3);
        p = fma((double)spkF[r2][k], (double)w2p[k], p);
      }
      p += __shfl_down(p, 4, 8);
      p += __shfl_down(p, 2, 8);
      p += __shfl_down(p, 1, 8);
      if (l == 0) {
        const float cur2 = __fadd_rn((float)p, b2v);
        const float rst2 = (m2 - 1.0f > 0.0f) ? 1.0f : 0.0f;
        const float mn2 =
            __fsub_rn(__fadd_rn(__fmul_rn(0.99f, m2), cur2), rst2);
        m2 = mn2;
        const size_t oidx = ((size_t)t * Bq + (gb + r2)) * Oq + o2;
        out[oidx] = (mn2 - 1.0f > 0.0f) ? 1.0f : 0.0f;  // spk2
        out[(size_t)Tq * Bq * Oq + oidx] = mn2;         // mem2
      }
    }
    // next step's rec only READS spkF before its barrier -> race-free
  }
}

extern "C" void kernel_launch(void* const* d_in, const int* in_sizes, int n_in,
                              void* d_out, int out_size, void* d_ws, size_t ws_size,
                              hipStream_t stream) {
  const float* x  = (const float*)d_in[0];
  const float* W1 = (const float*)d_in[1];
  const float* b1 = (const float*)d_in[2];
  const float* Wr = (const float*)d_in[3];
  const float* br = (const float*)d_in[4];
  const float* W2 = (const float*)d_in[5];
  const float* b2 = (const float*)d_in[6];
  float* out = (float*)d_out;  // FP32
  float* ws  = (float*)d_ws;   // cur1 chunk: nb*T*H f32
  (void)in_sizes; (void)n_in; (void)out_size;

  // largest power-of-2 batch-chunk whose cur1 fits in ws
  int nb = Bq;
  while (nb > 4 && (size_t)nb * Tq * Hq * sizeof(float) > ws_size) nb >>= 1;

  for (int b_off = 0; b_off < Bq; b_off += nb) {
    snn_fc1_gemm<<<dim3(Hq / 128, nb * Tq / 128), 256, 0, stream>>>(
        x + (size_t)b_off * Tq * Dq, W1, b1, ws);
    snn_scan<<<nb / 4, 512, 0, stream>>>(ws, Wr, br, W2, b2, out, b_off);
  }
}

// Round 15
// 3361.432 us; speedup vs baseline: 2.4014x; 1.0984x over previous
//
#include <hip/hip_runtime.h>

// Net_46076409152296: spiking net fwd (RLeaky+Leaky). B=1024,T=32,D=2312,H=512,O=10.
// v15: K1 = scalar-f64 tiled GEMM with f64 LDS staging (cvt hoisted out of the
// inner loop: 4 cvt/thread/slab instead of 128). Chunk-padded LDS layout
// ([8][160] doubles, chunk c at c*10) -> 2-way bank conflicts (free).
// NOTE: v14 proved mfma_f64 does NOT exist on gfx950 (module load failure) —
// scalar f64 at ~2cyc/wave-fma (measured v13) is the fast path.
// K2 + launcher verbatim from passing v13. All dots f64 (ascending k, identical
// fma order -> bit-identical results; absmax 0.1054688 expected).

constexpr int Bq = 1024, Tq = 32, Dq = 2312, Hq = 512, Oq = 10;

// ---------------- K1: C[m][n] = f64dot(x[m,:], W1[n,:]) + b1[n]
// 128x128 tile, 256 thr, 8x8 micro. LDS: f64, chunk-padded, double-buffered.
__global__ __launch_bounds__(256) void snn_fc1_gemm(
    const float* __restrict__ x, const float* __restrict__ W1,
    const float* __restrict__ b1, float* __restrict__ cur1) {
  // chunk c (8 doubles of rows c*8..c*8+7) lives at [kk][c*10 .. c*10+7]
  __shared__ double Xs[2][8][160];   // 20.5 KB
  __shared__ double Ws[2][8][160];   // 20.5 KB

  const int tid = threadIdx.x;
  const int tx = tid & 15;        // n dir
  const int ty = tid >> 4;        // m dir
  const size_t m0 = (size_t)blockIdx.y * 128;
  const int n0 = blockIdx.x * 128;
  const int srow = tid >> 1;             // staging row 0..127
  const int sko = (tid & 1) * 4;         // staging k offset 0 or 4
  const int schunk = (srow >> 3) * 10 + (srow & 7);  // padded position
  const float* __restrict__ ax = x + (m0 + srow) * Dq + sko;
  const float* __restrict__ bx = W1 + (size_t)(n0 + srow) * Dq + sko;

  double acc[8][8];
#pragma unroll
  for (int i = 0; i < 8; ++i)
#pragma unroll
    for (int j = 0; j < 8; ++j) acc[i][j] = 0.0;

  // prologue: stage slab 0 (cvt at staging — exact)
  float4 av = *(const float4*)(ax);
  float4 bv = *(const float4*)(bx);
  Xs[0][sko + 0][schunk] = (double)av.x;
  Xs[0][sko + 1][schunk] = (double)av.y;
  Xs[0][sko + 2][schunk] = (double)av.z;
  Xs[0][sko + 3][schunk] = (double)av.w;
  Ws[0][sko + 0][schunk] = (double)bv.x;
  Ws[0][sko + 1][schunk] = (double)bv.y;
  Ws[0][sko + 2][schunk] = (double)bv.z;
  Ws[0][sko + 3][schunk] = (double)bv.w;
  __syncthreads();

  for (int s = 0; s < 289; ++s) {        // D = 289 * 8
    const int buf = s & 1;
    if (s + 1 < 289) {                   // early-issue next slab's global loads
      av = *(const float4*)(ax + (s + 1) * 8);
      bv = *(const float4*)(bx + (s + 1) * 8);
    }
#pragma unroll
    for (int kk = 0; kk < 8; ++kk) {
      double a[8], b[8];
      *(double2*)&a[0] = *(const double2*)&Xs[buf][kk][ty * 10 + 0];
      *(double2*)&a[2] = *(const double2*)&Xs[buf][kk][ty * 10 + 2];
      *(double2*)&a[4] = *(const double2*)&Xs[buf][kk][ty * 10 + 4];
      *(double2*)&a[6] = *(const double2*)&Xs[buf][kk][ty * 10 + 6];
      *(double2*)&b[0] = *(const double2*)&Ws[buf][kk][tx * 10 + 0];
      *(double2*)&b[2] = *(const double2*)&Ws[buf][kk][tx * 10 + 2];
      *(double2*)&b[4] = *(const double2*)&Ws[buf][kk][tx * 10 + 4];
      *(double2*)&b[6] = *(const double2*)&Ws[buf][kk][tx * 10 + 6];
#pragma unroll
      for (int i = 0; i < 8; ++i)
#pragma unroll
        for (int j = 0; j < 8; ++j) acc[i][j] = fma(a[i], b[j], acc[i][j]);
    }
    if (s + 1 < 289) {
      const int nb = buf ^ 1;
      Xs[nb][sko + 0][schunk] = (double)av.x;
      Xs[nb][sko + 1][schunk] = (double)av.y;
      Xs[nb][sko + 2][schunk] = (double)av.z;
      Xs[nb][sko + 3][schunk] = (double)av.w;
      Ws[nb][sko + 0][schunk] = (double)bv.x;
      Ws[nb][sko + 1][schunk] = (double)bv.y;
      Ws[nb][sko + 2][schunk] = (double)bv.z;
      Ws[nb][sko + 3][schunk] = (double)bv.w;
      __syncthreads();
    }
  }

  float bl[8];
  *(float4*)&bl[0] = *(const float4*)(b1 + n0 + tx * 8);
  *(float4*)&bl[4] = *(const float4*)(b1 + n0 + tx * 8 + 4);
#pragma unroll
  for (int i = 0; i < 8; ++i) {
    float* crow = cur1 + (m0 + ty * 8 + i) * Hq + n0 + tx * 8;
    float4 v0, v1;
    v0.x = __fadd_rn((float)acc[i][0], bl[0]);
    v0.y = __fadd_rn((float)acc[i][1], bl[1]);
    v0.z = __fadd_rn((float)acc[i][2], bl[2]);
    v0.w = __fadd_rn((float)acc[i][3], bl[3]);
    v1.x = __fadd_rn((float)acc[i][4], bl[4]);
    v1.y = __fadd_rn((float)acc[i][5], bl[5]);
    v1.z = __fadd_rn((float)acc[i][6], bl[6]);
    v1.w = __fadd_rn((float)acc[i][7], bl[7]);
    *(float4*)(crow) = v0;
    *(float4*)(crow + 4) = v1;
  }
}

// ---------------- K2: recurrent scan (rec + mem1/spk + fc2 + outputs) — v13 verbatim
__global__ __launch_bounds__(512) void snn_scan(
    const float* __restrict__ cur1, const float* __restrict__ Wr,
    const float* __restrict__ br, const float* __restrict__ W2,
    const float* __restrict__ b2, float* __restrict__ out, int b_off) {
  __shared__ float spkF[4][512];   // 8 KB

  const int j = threadIdx.x;       // hidden unit
  const int lb = blockIdx.x * 4;   // local first row (within this ws chunk)
  const int gb = b_off + lb;       // global first batch row

  float m1[4] = {0.f, 0.f, 0.f, 0.f};
  float m2 = 0.f;
#pragma unroll
  for (int r = 0; r < 4; ++r) spkF[r][j] = 0.f;
  __syncthreads();

  const float brr = br[j];
  const float* __restrict__ wrp = Wr + (size_t)j * Hq;

  const int g = j >> 3, l = j & 7;
  const int r2 = g / 10, o2 = g - r2 * 10;
  const bool doB = (j < 320);
  const float b2v = doB ? b2[o2] : 0.f;
  const float* __restrict__ w2p = doB ? (W2 + (size_t)o2 * Hq) : W2;

  for (int t = 0; t < Tq; ++t) {
    float c1[4];
#pragma unroll
    for (int r = 0; r < 4; ++r)
      c1[r] = cur1[((size_t)(lb + r) * Tq + t) * Hq + j];

    double rec[4] = {0.0, 0.0, 0.0, 0.0};
    for (int k = 0; k < Hq; k += 4) {
      const float4 w4 = *(const float4*)(wrp + k);
      const double w0 = (double)w4.x, w1d = (double)w4.y;
      const double w2d = (double)w4.z, w3d = (double)w4.w;
#pragma unroll
      for (int r = 0; r < 4; ++r) {
        const float4 s4 = *(const float4*)&spkF[r][k];
        rec[r] = fma((double)s4.w, w3d,
                 fma((double)s4.z, w2d,
                 fma((double)s4.y, w1d, fma((double)s4.x, w0, rec[r]))));
      }
    }
    __syncthreads();  // all reads of old spikes complete
#pragma unroll
    for (int r = 0; r < 4; ++r) {
      const float rst = (m1[r] - 1.0f > 0.0f) ? 1.0f : 0.0f;
      const float mn = __fsub_rn(
          __fadd_rn(__fadd_rn(__fmul_rn(0.99f, m1[r]), c1[r]),
                    __fadd_rn((float)rec[r], brr)),
          rst);
      m1[r] = mn;
      spkF[r][j] = (mn - 1.0f > 0.0f) ? 1.0f : 0.0f;
    }
    __syncthreads();  // new spikes visible
    if (doB) {
      double p = 0.0;
#pragma unroll
      for (int s8 = 0; s8 < 64; ++s8) {
        const int k = l + (s8 << 3);
        p = fma((double)spkF[r2][k], (double)w2p[k], p);
      }
      p += __shfl_down(p, 4, 8);
      p += __shfl_down(p, 2, 8);
      p += __shfl_down(p, 1, 8);
      if (l == 0) {
        const float cur2 = __fadd_rn((float)p, b2v);
        const float rst2 = (m2 - 1.0f > 0.0f) ? 1.0f : 0.0f;
        const float mn2 =
            __fsub_rn(__fadd_rn(__fmul_rn(0.99f, m2), cur2), rst2);
        m2 = mn2;
        const size_t oidx = ((size_t)t * Bq + (gb + r2)) * Oq + o2;
        out[oidx] = (mn2 - 1.0f > 0.0f) ? 1.0f : 0.0f;  // spk2
        out[(size_t)Tq * Bq * Oq + oidx] = mn2;         // mem2
      }
    }
    // next step's rec only READS spkF before its barrier -> race-free
  }
}

extern "C" void kernel_launch(void* const* d_in, const int* in_sizes, int n_in,
                              void* d_out, int out_size, void* d_ws, size_t ws_size,
                              hipStream_t stream) {
  const float* x  = (const float*)d_in[0];
  const float* W1 = (const float*)d_in[1];
  const float* b1 = (const float*)d_in[2];
  const float* Wr = (const float*)d_in[3];
  const float* br = (const float*)d_in[4];
  const float* W2 = (const float*)d_in[5];
  const float* b2 = (const float*)d_in[6];
  float* out = (float*)d_out;  // FP32
  float* ws  = (float*)d_ws;   // cur1 chunk: nb*T*H f32
  (void)in_sizes; (void)n_in; (void)out_size;

  // largest power-of-2 batch-chunk whose cur1 fits in ws
  int nb = Bq;
  while (nb > 4 && (size_t)nb * Tq * Hq * sizeof(float) > ws_size) nb >>= 1;

  for (int b_off = 0; b_off < Bq; b_off += nb) {
    snn_fc1_gemm<<<dim3(Hq / 128, nb * Tq / 128), 256, 0, stream>>>(
        x + (size_t)b_off * Tq * Dq, W1, b1, ws);
    snn_scan<<<nb / 4, 512, 0, stream>>>(ws, Wr, br, W2, b2, out, b_off);
  }
}